// Round 1
// baseline (263.512 us; speedup 1.0000x reference)
//
#include <hip/hip_runtime.h>

// B=4, S=4096, D_IN=1024, D_QK=D_V=64
// out = softmax(relu(XWq+bq) @ relu(XWk+bk)^T) @ relu(XWv+bv) * mask

typedef short s16x8 __attribute__((ext_vector_type(8)));   // 8 bf16 (4 VGPRs) MFMA frag
typedef float fx4   __attribute__((ext_vector_type(4)));   // MFMA accum frag
typedef unsigned short u16x4 __attribute__((ext_vector_type(4)));

#define LOG2E 1.4426950408889634f

__device__ __forceinline__ unsigned short f2bf(float x) {   // fp32 -> bf16 RTN
    unsigned int u = __float_as_uint(x);
    u += 0x7FFFu + ((u >> 16) & 1u);
    return (unsigned short)(u >> 16);
}
__device__ __forceinline__ float bf2f(unsigned short b) {
    return __uint_as_float(((unsigned int)b) << 16);
}

// ---------------------------------------------------------------------------
// Kernel 1: split W{q,k,v} [1024][64] fp32 into W^T hi/lo bf16 [3][64][1024]
// ---------------------------------------------------------------------------
__global__ __launch_bounds__(256) void prep_w_kernel(
    const float* __restrict__ Wq, const float* __restrict__ Wk, const float* __restrict__ Wv,
    unsigned short* __restrict__ wt_hi, unsigned short* __restrict__ wt_lo)
{
    int idx = blockIdx.x * 256 + threadIdx.x;   // 3*1024*64 = 196608 threads
    int y = idx >> 16;
    int r = idx & 65535;
    int k = r >> 6;
    int c = r & 63;
    const float* W = (y == 0) ? Wq : (y == 1) ? Wk : Wv;
    float x = W[r];
    unsigned short h = f2bf(x);
    unsigned short l = f2bf(x - bf2f(h));
    int o = (y * 64 + c) * 1024 + k;
    wt_hi[o] = h; wt_lo[o] = l;
}

// ---------------------------------------------------------------------------
// Kernel 2: projection. grid (3, 128): x = which matrix (q/k/v), y = m-tile.
// Computes 128 rows x 64 cols with compensated bf16 MFMA (hh+hl+lh ~ fp32).
// y==0 -> q_hi/q_lo bf16; y==1 -> k bf16; y==2 -> V^T [b][d][s] bf16.
// ---------------------------------------------------------------------------
__global__ __launch_bounds__(256) void proj_kernel(
    const float* __restrict__ X,
    const unsigned short* __restrict__ wt_hi, const unsigned short* __restrict__ wt_lo,
    const float* __restrict__ bq, const float* __restrict__ bk, const float* __restrict__ bv,
    unsigned short* __restrict__ q_hi, unsigned short* __restrict__ q_lo,
    unsigned short* __restrict__ k_bf, unsigned short* __restrict__ vt_g)
{
    __shared__ __align__(16) unsigned short a_hi[128][72];  // X tile hi, +8 pad (2-way banks)
    __shared__ __align__(16) unsigned short a_lo[128][72];
    __shared__ __align__(16) unsigned short b_hi[64][72];   // W^T tile hi [col][k]
    __shared__ __align__(16) unsigned short b_lo[64][72];

    const int tid  = threadIdx.x;
    const int lane = tid & 63;
    const int w    = tid >> 6;
    const int quad = lane >> 4;
    const int l15  = lane & 15;
    const int y    = blockIdx.x;        // 0=q 1=k 2=v
    const int m0   = blockIdx.y * 128;  // global row (b*4096+s)

    fx4 acc[2][4];
    #pragma unroll
    for (int st = 0; st < 2; st++)
        #pragma unroll
        for (int nt = 0; nt < 4; nt++)
            acc[st][nt] = (fx4){0.f, 0.f, 0.f, 0.f};

    for (int kc = 0; kc < 16; kc++) {
        // stage X tile 128x64 fp32 -> hi/lo bf16 in LDS (coalesced 16B reads)
        #pragma unroll
        for (int i = 0; i < 8; i++) {
            int c = tid + i * 256;
            int row = c >> 4;
            int off = (c & 15) * 4;
            const float* src = X + (size_t)(m0 + row) * 1024 + kc * 64 + off;
            fx4 xv = *(const fx4*)src;
            unsigned short h0 = f2bf(xv.x), h1 = f2bf(xv.y), h2 = f2bf(xv.z), h3 = f2bf(xv.w);
            unsigned short l0 = f2bf(xv.x - bf2f(h0)), l1 = f2bf(xv.y - bf2f(h1));
            unsigned short l2 = f2bf(xv.z - bf2f(h2)), l3 = f2bf(xv.w - bf2f(h3));
            *(u16x4*)&a_hi[row][off] = (u16x4){h0, h1, h2, h3};
            *(u16x4*)&a_lo[row][off] = (u16x4){l0, l1, l2, l3};
        }
        // stage W^T tile 64x64 (pre-split, coalesced 16B reads)
        #pragma unroll
        for (int i = 0; i < 2; i++) {
            int c = tid + i * 256;
            int row = c >> 3;
            int off = (c & 7) * 8;
            size_t g = (size_t)(y * 64 + row) * 1024 + kc * 64 + off;
            *(s16x8*)&b_hi[row][off] = *(const s16x8*)(wt_hi + g);
            *(s16x8*)&b_lo[row][off] = *(const s16x8*)(wt_lo + g);
        }
        __syncthreads();

        s16x8 ah[2][2], al[2][2];
        #pragma unroll
        for (int st = 0; st < 2; st++)
            #pragma unroll
            for (int ks = 0; ks < 2; ks++) {
                int r = w * 32 + st * 16 + l15;
                ah[st][ks] = *(const s16x8*)&a_hi[r][ks * 32 + quad * 8];
                al[st][ks] = *(const s16x8*)&a_lo[r][ks * 32 + quad * 8];
            }
        #pragma unroll
        for (int nt = 0; nt < 4; nt++) {
            #pragma unroll
            for (int ks = 0; ks < 2; ks++) {
                s16x8 bh = *(const s16x8*)&b_hi[nt * 16 + l15][ks * 32 + quad * 8];
                s16x8 bl = *(const s16x8*)&b_lo[nt * 16 + l15][ks * 32 + quad * 8];
                #pragma unroll
                for (int st = 0; st < 2; st++) {
                    acc[st][nt] = __builtin_amdgcn_mfma_f32_16x16x32_bf16(ah[st][ks], bh, acc[st][nt], 0, 0, 0);
                    acc[st][nt] = __builtin_amdgcn_mfma_f32_16x16x32_bf16(ah[st][ks], bl, acc[st][nt], 0, 0, 0);
                    acc[st][nt] = __builtin_amdgcn_mfma_f32_16x16x32_bf16(al[st][ks], bh, acc[st][nt], 0, 0, 0);
                }
            }
        }
        __syncthreads();
    }

    // epilogue: bias + relu, write per-matrix
    const float* bias = (y == 0) ? bq : (y == 1) ? bk : bv;
    const int b   = m0 >> 12;
    const int s0b = m0 & 4095;
    unsigned short* vtr = (unsigned short*)&a_hi[0][0];  // alias: [64 d][136] (s-padded)

    #pragma unroll
    for (int nt = 0; nt < 4; nt++) {
        int col = nt * 16 + l15;
        float bb = bias[col];
        #pragma unroll
        for (int st = 0; st < 2; st++) {
            int rloc = w * 32 + st * 16 + quad * 4;   // local row 0..127
            #pragma unroll
            for (int r = 0; r < 4; r++) {
                float v = acc[st][nt][r] + bb;
                v = fmaxf(v, 0.f);
                size_t grow = (size_t)(m0 + rloc + r);
                if (y == 0) {
                    unsigned short h = f2bf(v);
                    unsigned short l = f2bf(v - bf2f(h));
                    q_hi[grow * 64 + col] = h;
                    q_lo[grow * 64 + col] = l;
                } else if (y == 1) {
                    k_bf[grow * 64 + col] = f2bf(v);
                } else {
                    vtr[col * 136 + rloc + r] = f2bf(v);  // transpose via LDS
                }
            }
        }
    }
    if (y == 2) {
        __syncthreads();
        #pragma unroll
        for (int i = 0; i < 4; i++) {
            int c = tid + i * 256;
            int row = c >> 4;           // d
            int off = (c & 15) * 8;     // s chunk
            s16x8 vv = *(const s16x8*)&vtr[row * 136 + off];
            *(s16x8*)(vt_g + (size_t)(b * 64 + row) * 4096 + s0b + off) = vv;
        }
    }
}

// ---------------------------------------------------------------------------
// Kernel 3: fused attention. grid 256 = b*64 + q-tile(64 rows). 4 waves x 16 q.
// No online max: q,k >= 0 post-relu => scores in [0, ~20], exp safe in fp32.
// ---------------------------------------------------------------------------
__global__ __launch_bounds__(256) void attn_kernel(
    const unsigned short* __restrict__ q_hi, const unsigned short* __restrict__ q_lo,
    const unsigned short* __restrict__ k_bf, const unsigned short* __restrict__ vt_g,
    const float* __restrict__ mask, float* __restrict__ out)
{
    __shared__ __align__(16) unsigned short kt[64][72];      // [key][dim]
    __shared__ __align__(16) unsigned short vt[64][72];      // [dim][key]  (V^T)
    __shared__ __align__(16) unsigned short pt[4][16][72];   // per-wave P [q][key]

    const int tid  = threadIdx.x;
    const int lane = tid & 63;
    const int w    = tid >> 6;
    const int quad = lane >> 4;
    const int l15  = lane & 15;
    const int b    = blockIdx.x >> 6;
    const int q0   = (blockIdx.x & 63) * 64;   // within batch

    // Q fragments (A layout: m=lane&15, k=quad*8+j), split hi/lo
    const size_t qoff = ((size_t)b * 4096 + q0 + w * 16 + l15) * 64 + quad * 8;
    s16x8 qh0 = *(const s16x8*)(q_hi + qoff);
    s16x8 qh1 = *(const s16x8*)(q_hi + qoff + 32);
    s16x8 ql0 = *(const s16x8*)(q_lo + qoff);
    s16x8 ql1 = *(const s16x8*)(q_lo + qoff + 32);

    fx4 accO[4];
    #pragma unroll
    for (int nt = 0; nt < 4; nt++) accO[nt] = (fx4){0.f, 0.f, 0.f, 0.f};
    float lpart[4] = {0.f, 0.f, 0.f, 0.f};

    const unsigned short* kgb = k_bf + (size_t)b * 4096 * 64;  // [s][64]
    const unsigned short* vgb = vt_g + (size_t)b * 64 * 4096;  // [d][s]

    for (int it = 0; it < 64; it++) {
        const unsigned short* kg = kgb + (size_t)it * 4096;    // 64 keys x 64 dims, contiguous
        #pragma unroll
        for (int i = 0; i < 2; i++) {
            int c = tid + i * 256;
            int row = c >> 3;
            int off = (c & 7) * 8;
            *(s16x8*)&kt[row][off] = *(const s16x8*)(kg + c * 8);
            *(s16x8*)&vt[row][off] = *(const s16x8*)(vgb + (size_t)row * 4096 + it * 64 + off);
        }
        __syncthreads();

        // S = Q K^T  (q hi/lo compensated)
        fx4 sc[4];
        #pragma unroll
        for (int nt = 0; nt < 4; nt++) sc[nt] = (fx4){0.f, 0.f, 0.f, 0.f};
        #pragma unroll
        for (int nt = 0; nt < 4; nt++) {
            s16x8 k0 = *(const s16x8*)&kt[nt * 16 + l15][quad * 8];
            s16x8 k1 = *(const s16x8*)&kt[nt * 16 + l15][32 + quad * 8];
            sc[nt] = __builtin_amdgcn_mfma_f32_16x16x32_bf16(qh0, k0, sc[nt], 0, 0, 0);
            sc[nt] = __builtin_amdgcn_mfma_f32_16x16x32_bf16(ql0, k0, sc[nt], 0, 0, 0);
            sc[nt] = __builtin_amdgcn_mfma_f32_16x16x32_bf16(qh1, k1, sc[nt], 0, 0, 0);
            sc[nt] = __builtin_amdgcn_mfma_f32_16x16x32_bf16(ql1, k1, sc[nt], 0, 0, 0);
        }

        // P = exp(S); accumulate row-sums per-lane; P -> LDS (C layout -> A layout)
        #pragma unroll
        for (int nt = 0; nt < 4; nt++) {
            #pragma unroll
            for (int r = 0; r < 4; r++) {
                float p = __builtin_amdgcn_exp2f(sc[nt][r] * LOG2E);
                unsigned short pb = f2bf(p);
                lpart[r] += bf2f(pb);   // denominator matches bf16-rounded numerator
                pt[w][quad * 4 + r][nt * 16 + l15] = pb;
            }
        }

        // O += P V
        s16x8 pa0 = *(const s16x8*)&pt[w][l15][quad * 8];
        s16x8 pa1 = *(const s16x8*)&pt[w][l15][32 + quad * 8];
        #pragma unroll
        for (int nt = 0; nt < 4; nt++) {
            s16x8 v0 = *(const s16x8*)&vt[nt * 16 + l15][quad * 8];
            s16x8 v1 = *(const s16x8*)&vt[nt * 16 + l15][32 + quad * 8];
            accO[nt] = __builtin_amdgcn_mfma_f32_16x16x32_bf16(pa0, v0, accO[nt], 0, 0, 0);
            accO[nt] = __builtin_amdgcn_mfma_f32_16x16x32_bf16(pa1, v1, accO[nt], 0, 0, 0);
        }
        __syncthreads();
    }

    // reduce row-sums across the 16 lanes sharing each row group
    #pragma unroll
    for (int r = 0; r < 4; r++) {
        float v = lpart[r];
        #pragma unroll
        for (int o = 1; o < 16; o <<= 1) v += __shfl_xor(v, o);
        lpart[r] = v;
    }
    #pragma unroll
    for (int r = 0; r < 4; r++) {
        int qrow = q0 + w * 16 + quad * 4 + r;
        float mk  = mask[(size_t)b * 4096 + qrow];
        float inv = mk / lpart[r];
        #pragma unroll
        for (int nt = 0; nt < 4; nt++)
            out[((size_t)b * 4096 + qrow) * 64 + nt * 16 + l15] = accO[nt][r] * inv;
    }
}

// ---------------------------------------------------------------------------
extern "C" void kernel_launch(void* const* d_in, const int* in_sizes, int n_in,
                              void* d_out, int out_size, void* d_ws, size_t ws_size,
                              hipStream_t stream)
{
    const float* X    = (const float*)d_in[0];
    const float* mask = (const float*)d_in[1];
    const float* Wq   = (const float*)d_in[2];
    const float* bq   = (const float*)d_in[3];
    const float* Wk   = (const float*)d_in[4];
    const float* bk   = (const float*)d_in[5];
    const float* Wv   = (const float*)d_in[6];
    const float* bv   = (const float*)d_in[7];
    float* out = (float*)d_out;

    char* ws = (char*)d_ws;
    unsigned short* q_hi  = (unsigned short*)(ws);                       // 2 MB
    unsigned short* q_lo  = (unsigned short*)(ws + (size_t)(2u << 20));  // 2 MB
    unsigned short* k_bf  = (unsigned short*)(ws + (size_t)(4u << 20));  // 2 MB
    unsigned short* vt_g  = (unsigned short*)(ws + (size_t)(6u << 20));  // 2 MB  [b][d][s]
    unsigned short* wt_hi = (unsigned short*)(ws + (size_t)(8u << 20));  // 384 KB
    unsigned short* wt_lo = (unsigned short*)(ws + (size_t)(8u << 20) + 393216);

    hipLaunchKernelGGL(prep_w_kernel, dim3(768), dim3(256), 0, stream,
                       Wq, Wk, Wv, wt_hi, wt_lo);
    hipLaunchKernelGGL(proj_kernel, dim3(3, 128), dim3(256), 0, stream,
                       X, wt_hi, wt_lo, bq, bk, bv, q_hi, q_lo, k_bf, vt_g);
    hipLaunchKernelGGL(attn_kernel, dim3(256), dim3(256), 0, stream,
                       q_hi, q_lo, k_bf, vt_g, mask, out);
}

// Round 2
// 193.327 us; speedup vs baseline: 1.3630x; 1.3630x over previous
//
#include <hip/hip_runtime.h>

// B=4, S=4096, D_IN=1024, D_QK=D_V=64
// out = softmax(relu(XWq+bq) @ relu(XWk+bk)^T) @ relu(XWv+bv) * mask

typedef short s16x8 __attribute__((ext_vector_type(8)));   // 8 bf16 (4 VGPRs) MFMA frag
typedef float fx4   __attribute__((ext_vector_type(4)));   // MFMA accum frag
typedef unsigned short u16x4 __attribute__((ext_vector_type(4)));

#define LOG2E 1.4426950408889634f

__device__ __forceinline__ unsigned short f2bf(float x) {   // fp32 -> bf16 RTN
    unsigned int u = __float_as_uint(x);
    u += 0x7FFFu + ((u >> 16) & 1u);
    return (unsigned short)(u >> 16);
}
__device__ __forceinline__ float bf2f(unsigned short b) {
    return __uint_as_float(((unsigned int)b) << 16);
}

// ---------------------------------------------------------------------------
// Kernel 1: split W{q,k,v} [1024][64] fp32 into W^T hi/lo bf16 [3][64][1024]
// ---------------------------------------------------------------------------
__global__ __launch_bounds__(256) void prep_w_kernel(
    const float* __restrict__ Wq, const float* __restrict__ Wk, const float* __restrict__ Wv,
    unsigned short* __restrict__ wt_hi, unsigned short* __restrict__ wt_lo)
{
    int idx = blockIdx.x * 256 + threadIdx.x;   // 3*1024*64 = 196608 threads
    int y = idx >> 16;
    int r = idx & 65535;
    int k = r >> 6;
    int c = r & 63;
    const float* W = (y == 0) ? Wq : (y == 1) ? Wk : Wv;
    float x = W[r];
    unsigned short h = f2bf(x);
    unsigned short l = f2bf(x - bf2f(h));
    int o = (y * 64 + c) * 1024 + k;
    wt_hi[o] = h; wt_lo[o] = l;
}

// ---------------------------------------------------------------------------
// Kernel 2: projection. grid (3, 128): x = which matrix (q/k/v), y = m-tile.
// Computes 128 rows x 64 cols with compensated bf16 MFMA (hh+hl+lh ~ fp32).
// y==0 -> q_hi/q_lo bf16; y==1 -> k bf16; y==2 -> V^T [b][d][s] bf16.
// (unchanged this round so its counters surface in the next profile)
// ---------------------------------------------------------------------------
__global__ __launch_bounds__(256) void proj_kernel(
    const float* __restrict__ X,
    const unsigned short* __restrict__ wt_hi, const unsigned short* __restrict__ wt_lo,
    const float* __restrict__ bq, const float* __restrict__ bk, const float* __restrict__ bv,
    unsigned short* __restrict__ q_hi, unsigned short* __restrict__ q_lo,
    unsigned short* __restrict__ k_bf, unsigned short* __restrict__ vt_g)
{
    __shared__ __align__(16) unsigned short a_hi[128][72];  // X tile hi, +8 pad (2-way banks)
    __shared__ __align__(16) unsigned short a_lo[128][72];
    __shared__ __align__(16) unsigned short b_hi[64][72];   // W^T tile hi [col][k]
    __shared__ __align__(16) unsigned short b_lo[64][72];

    const int tid  = threadIdx.x;
    const int lane = tid & 63;
    const int w    = tid >> 6;
    const int quad = lane >> 4;
    const int l15  = lane & 15;
    const int y    = blockIdx.x;        // 0=q 1=k 2=v
    const int m0   = blockIdx.y * 128;  // global row (b*4096+s)

    fx4 acc[2][4];
    #pragma unroll
    for (int st = 0; st < 2; st++)
        #pragma unroll
        for (int nt = 0; nt < 4; nt++)
            acc[st][nt] = (fx4){0.f, 0.f, 0.f, 0.f};

    for (int kc = 0; kc < 16; kc++) {
        // stage X tile 128x64 fp32 -> hi/lo bf16 in LDS (coalesced 16B reads)
        #pragma unroll
        for (int i = 0; i < 8; i++) {
            int c = tid + i * 256;
            int row = c >> 4;
            int off = (c & 15) * 4;
            const float* src = X + (size_t)(m0 + row) * 1024 + kc * 64 + off;
            fx4 xv = *(const fx4*)src;
            unsigned short h0 = f2bf(xv.x), h1 = f2bf(xv.y), h2 = f2bf(xv.z), h3 = f2bf(xv.w);
            unsigned short l0 = f2bf(xv.x - bf2f(h0)), l1 = f2bf(xv.y - bf2f(h1));
            unsigned short l2 = f2bf(xv.z - bf2f(h2)), l3 = f2bf(xv.w - bf2f(h3));
            *(u16x4*)&a_hi[row][off] = (u16x4){h0, h1, h2, h3};
            *(u16x4*)&a_lo[row][off] = (u16x4){l0, l1, l2, l3};
        }
        // stage W^T tile 64x64 (pre-split, coalesced 16B reads)
        #pragma unroll
        for (int i = 0; i < 2; i++) {
            int c = tid + i * 256;
            int row = c >> 3;
            int off = (c & 7) * 8;
            size_t g = (size_t)(y * 64 + row) * 1024 + kc * 64 + off;
            *(s16x8*)&b_hi[row][off] = *(const s16x8*)(wt_hi + g);
            *(s16x8*)&b_lo[row][off] = *(const s16x8*)(wt_lo + g);
        }
        __syncthreads();

        s16x8 ah[2][2], al[2][2];
        #pragma unroll
        for (int st = 0; st < 2; st++)
            #pragma unroll
            for (int ks = 0; ks < 2; ks++) {
                int r = w * 32 + st * 16 + l15;
                ah[st][ks] = *(const s16x8*)&a_hi[r][ks * 32 + quad * 8];
                al[st][ks] = *(const s16x8*)&a_lo[r][ks * 32 + quad * 8];
            }
        #pragma unroll
        for (int nt = 0; nt < 4; nt++) {
            #pragma unroll
            for (int ks = 0; ks < 2; ks++) {
                s16x8 bh = *(const s16x8*)&b_hi[nt * 16 + l15][ks * 32 + quad * 8];
                s16x8 bl = *(const s16x8*)&b_lo[nt * 16 + l15][ks * 32 + quad * 8];
                #pragma unroll
                for (int st = 0; st < 2; st++) {
                    acc[st][nt] = __builtin_amdgcn_mfma_f32_16x16x32_bf16(ah[st][ks], bh, acc[st][nt], 0, 0, 0);
                    acc[st][nt] = __builtin_amdgcn_mfma_f32_16x16x32_bf16(ah[st][ks], bl, acc[st][nt], 0, 0, 0);
                    acc[st][nt] = __builtin_amdgcn_mfma_f32_16x16x32_bf16(al[st][ks], bh, acc[st][nt], 0, 0, 0);
                }
            }
        }
        __syncthreads();
    }

    // epilogue: bias + relu, write per-matrix
    const float* bias = (y == 0) ? bq : (y == 1) ? bk : bv;
    const int b   = m0 >> 12;
    const int s0b = m0 & 4095;
    unsigned short* vtr = (unsigned short*)&a_hi[0][0];  // alias: [64 d][136] (s-padded)

    #pragma unroll
    for (int nt = 0; nt < 4; nt++) {
        int col = nt * 16 + l15;
        float bb = bias[col];
        #pragma unroll
        for (int st = 0; st < 2; st++) {
            int rloc = w * 32 + st * 16 + quad * 4;   // local row 0..127
            #pragma unroll
            for (int r = 0; r < 4; r++) {
                float v = acc[st][nt][r] + bb;
                v = fmaxf(v, 0.f);
                size_t grow = (size_t)(m0 + rloc + r);
                if (y == 0) {
                    unsigned short h = f2bf(v);
                    unsigned short l = f2bf(v - bf2f(h));
                    q_hi[grow * 64 + col] = h;
                    q_lo[grow * 64 + col] = l;
                } else if (y == 1) {
                    k_bf[grow * 64 + col] = f2bf(v);
                } else {
                    vtr[col * 136 + rloc + r] = f2bf(v);  // transpose via LDS
                }
            }
        }
    }
    if (y == 2) {
        __syncthreads();
        #pragma unroll
        for (int i = 0; i < 4; i++) {
            int c = tid + i * 256;
            int row = c >> 4;           // d
            int off = (c & 15) * 8;     // s chunk
            s16x8 vv = *(const s16x8*)&vtr[row * 136 + off];
            *(s16x8*)(vt_g + (size_t)(b * 64 + row) * 4096 + s0b + off) = vv;
        }
    }
}

// ---------------------------------------------------------------------------
// Kernel 3: fused attention, KV-split. grid 1024 = (b,4)(chunk,4)(qtile,64).
// Each block: 64 q-rows x 1024 keys (16 KV tiles). Writes UNNORMALIZED
// partial O and partial row-sum l; combine kernel reduces over chunks.
// No online max: q,k >= 0 post-relu => scores in [0, ~20], exp safe in fp32,
// partials combine by pure addition.
// ---------------------------------------------------------------------------
__global__ __launch_bounds__(256) void attn_kernel(
    const unsigned short* __restrict__ q_hi, const unsigned short* __restrict__ q_lo,
    const unsigned short* __restrict__ k_bf, const unsigned short* __restrict__ vt_g,
    float* __restrict__ pO, float* __restrict__ pL)
{
    __shared__ __align__(16) unsigned short kt[64][72];      // [key][dim]
    __shared__ __align__(16) unsigned short vt[64][72];      // [dim][key]  (V^T)
    __shared__ __align__(16) unsigned short pt[4][16][72];   // per-wave P [q][key]

    const int tid  = threadIdx.x;
    const int lane = tid & 63;
    const int w    = tid >> 6;
    const int quad = lane >> 4;
    const int l15  = lane & 15;
    const int idx  = blockIdx.x;
    const int qt   = idx & 63;
    const int ck   = (idx >> 6) & 3;     // key chunk (1024 keys)
    const int b    = idx >> 8;
    const int q0   = qt * 64;            // within batch

    // Q fragments (A layout: m=lane&15, k=quad*8+j), split hi/lo
    const size_t qoff = ((size_t)b * 4096 + q0 + w * 16 + l15) * 64 + quad * 8;
    s16x8 qh0 = *(const s16x8*)(q_hi + qoff);
    s16x8 qh1 = *(const s16x8*)(q_hi + qoff + 32);
    s16x8 ql0 = *(const s16x8*)(q_lo + qoff);
    s16x8 ql1 = *(const s16x8*)(q_lo + qoff + 32);

    fx4 accO[4];
    #pragma unroll
    for (int nt = 0; nt < 4; nt++) accO[nt] = (fx4){0.f, 0.f, 0.f, 0.f};
    float lpart[4] = {0.f, 0.f, 0.f, 0.f};

    const unsigned short* kgb = k_bf + (size_t)b * 4096 * 64;  // [s][64]
    const unsigned short* vgb = vt_g + (size_t)b * 64 * 4096;  // [d][s]

    for (int it = ck * 16; it < ck * 16 + 16; it++) {
        const unsigned short* kg = kgb + (size_t)it * 4096;    // 64 keys x 64 dims, contiguous
        #pragma unroll
        for (int i = 0; i < 2; i++) {
            int c = tid + i * 256;
            int row = c >> 3;
            int off = (c & 7) * 8;
            *(s16x8*)&kt[row][off] = *(const s16x8*)(kg + c * 8);
            *(s16x8*)&vt[row][off] = *(const s16x8*)(vgb + (size_t)row * 4096 + it * 64 + off);
        }
        __syncthreads();

        // S = Q K^T  (q hi/lo compensated)
        fx4 sc[4];
        #pragma unroll
        for (int nt = 0; nt < 4; nt++) sc[nt] = (fx4){0.f, 0.f, 0.f, 0.f};
        #pragma unroll
        for (int nt = 0; nt < 4; nt++) {
            s16x8 k0 = *(const s16x8*)&kt[nt * 16 + l15][quad * 8];
            s16x8 k1 = *(const s16x8*)&kt[nt * 16 + l15][32 + quad * 8];
            sc[nt] = __builtin_amdgcn_mfma_f32_16x16x32_bf16(qh0, k0, sc[nt], 0, 0, 0);
            sc[nt] = __builtin_amdgcn_mfma_f32_16x16x32_bf16(ql0, k0, sc[nt], 0, 0, 0);
            sc[nt] = __builtin_amdgcn_mfma_f32_16x16x32_bf16(qh1, k1, sc[nt], 0, 0, 0);
            sc[nt] = __builtin_amdgcn_mfma_f32_16x16x32_bf16(ql1, k1, sc[nt], 0, 0, 0);
        }

        // P = exp(S); accumulate row-sums per-lane; P -> LDS (C layout -> A layout)
        #pragma unroll
        for (int nt = 0; nt < 4; nt++) {
            #pragma unroll
            for (int r = 0; r < 4; r++) {
                float p = __builtin_amdgcn_exp2f(sc[nt][r] * LOG2E);
                unsigned short pb = f2bf(p);
                lpart[r] += bf2f(pb);   // denominator matches bf16-rounded numerator
                pt[w][quad * 4 + r][nt * 16 + l15] = pb;
            }
        }

        // O += P V
        s16x8 pa0 = *(const s16x8*)&pt[w][l15][quad * 8];
        s16x8 pa1 = *(const s16x8*)&pt[w][l15][32 + quad * 8];
        #pragma unroll
        for (int nt = 0; nt < 4; nt++) {
            s16x8 v0 = *(const s16x8*)&vt[nt * 16 + l15][quad * 8];
            s16x8 v1 = *(const s16x8*)&vt[nt * 16 + l15][32 + quad * 8];
            accO[nt] = __builtin_amdgcn_mfma_f32_16x16x32_bf16(pa0, v0, accO[nt], 0, 0, 0);
            accO[nt] = __builtin_amdgcn_mfma_f32_16x16x32_bf16(pa1, v1, accO[nt], 0, 0, 0);
        }
        __syncthreads();
    }

    // reduce row-sums across the 16 lanes sharing each row group
    #pragma unroll
    for (int r = 0; r < 4; r++) {
        float v = lpart[r];
        #pragma unroll
        for (int o = 1; o < 16; o <<= 1) v += __shfl_xor(v, o);
        lpart[r] = v;
    }
    // write partials: pO[ck][b*4096+q][64], pL[ck][b*4096+q]
    #pragma unroll
    for (int r = 0; r < 4; r++) {
        int qrow = q0 + w * 16 + quad * 4 + r;
        size_t grow = (size_t)b * 4096 + qrow;
        #pragma unroll
        for (int nt = 0; nt < 4; nt++)
            pO[((size_t)ck * 16384 + grow) * 64 + nt * 16 + l15] = accO[nt][r];
        if (l15 == 0)
            pL[(size_t)ck * 16384 + grow] = lpart[r];
    }
}

// ---------------------------------------------------------------------------
// Kernel 4: combine partials: out = (sum_c pO) * mask / (sum_c pL)
// ---------------------------------------------------------------------------
__global__ __launch_bounds__(256) void combine_kernel(
    const float* __restrict__ pO, const float* __restrict__ pL,
    const float* __restrict__ mask, float* __restrict__ out)
{
    int idx = blockIdx.x * 256 + threadIdx.x;   // 262144 = (b*4096+s)*16 + dgrp
    int q  = idx >> 4;
    int dg = idx & 15;
    fx4 s = (fx4){0.f, 0.f, 0.f, 0.f};
    float l = 0.f;
    #pragma unroll
    for (int c = 0; c < 4; c++) {
        s += *(const fx4*)(pO + ((size_t)c * 16384 + q) * 64 + dg * 4);
        l += pL[(size_t)c * 16384 + q];
    }
    float scale = mask[q] / l;
    *(fx4*)(out + (size_t)q * 64 + dg * 4) = s * scale;
}

// ---------------------------------------------------------------------------
extern "C" void kernel_launch(void* const* d_in, const int* in_sizes, int n_in,
                              void* d_out, int out_size, void* d_ws, size_t ws_size,
                              hipStream_t stream)
{
    const float* X    = (const float*)d_in[0];
    const float* mask = (const float*)d_in[1];
    const float* Wq   = (const float*)d_in[2];
    const float* bq   = (const float*)d_in[3];
    const float* Wk   = (const float*)d_in[4];
    const float* bk   = (const float*)d_in[5];
    const float* Wv   = (const float*)d_in[6];
    const float* bv   = (const float*)d_in[7];
    float* out = (float*)d_out;

    char* ws = (char*)d_ws;
    unsigned short* q_hi  = (unsigned short*)(ws);                       // 2 MB
    unsigned short* q_lo  = (unsigned short*)(ws + (size_t)(2u << 20));  // 2 MB
    unsigned short* k_bf  = (unsigned short*)(ws + (size_t)(4u << 20));  // 2 MB
    unsigned short* vt_g  = (unsigned short*)(ws + (size_t)(6u << 20));  // 2 MB  [b][d][s]
    unsigned short* wt_hi = (unsigned short*)(ws + (size_t)(8u << 20));  // 384 KB
    unsigned short* wt_lo = (unsigned short*)(ws + (size_t)(8u << 20) + 393216);
    float*          pO    = (float*)(ws + (size_t)(9u << 20));           // 16 MB [4][16384][64]
    float*          pL    = (float*)(ws + (size_t)(25u << 20));          // 256 KB [4][16384]

    hipLaunchKernelGGL(prep_w_kernel, dim3(768), dim3(256), 0, stream,
                       Wq, Wk, Wv, wt_hi, wt_lo);
    hipLaunchKernelGGL(proj_kernel, dim3(3, 128), dim3(256), 0, stream,
                       X, wt_hi, wt_lo, bq, bk, bv, q_hi, q_lo, k_bf, vt_g);
    hipLaunchKernelGGL(attn_kernel, dim3(1024), dim3(256), 0, stream,
                       q_hi, q_lo, k_bf, vt_g, pO, pL);
    hipLaunchKernelGGL(combine_kernel, dim3(1024), dim3(256), 0, stream,
                       pO, pL, mask, out);
}

// Round 3
// 185.159 us; speedup vs baseline: 1.4232x; 1.0441x over previous
//
#include <hip/hip_runtime.h>

// B=4, S=4096, D_IN=1024, D_QK=D_V=64
// out = softmax(relu(XWq+bq) @ relu(XWk+bk)^T) @ relu(XWv+bv) * mask

typedef short s16x8 __attribute__((ext_vector_type(8)));   // 8 bf16 (4 VGPRs) MFMA frag
typedef float fx4   __attribute__((ext_vector_type(4)));   // MFMA accum frag
typedef unsigned short u16x4 __attribute__((ext_vector_type(4)));

#define LOG2E 1.4426950408889634f

__device__ __forceinline__ unsigned short f2bf(float x) {   // fp32 -> bf16 RTN
    unsigned int u = __float_as_uint(x);
    u += 0x7FFFu + ((u >> 16) & 1u);
    return (unsigned short)(u >> 16);
}
__device__ __forceinline__ float bf2f(unsigned short b) {
    return __uint_as_float(((unsigned int)b) << 16);
}

// ---------------------------------------------------------------------------
// Kernel 1: split W{q,k,v} [1024][64] fp32 into W^T hi/lo bf16 [3][64][1024]
// ---------------------------------------------------------------------------
__global__ __launch_bounds__(256) void prep_w_kernel(
    const float* __restrict__ Wq, const float* __restrict__ Wk, const float* __restrict__ Wv,
    unsigned short* __restrict__ wt_hi, unsigned short* __restrict__ wt_lo)
{
    int idx = blockIdx.x * 256 + threadIdx.x;   // 3*1024*64 = 196608 threads
    int y = idx >> 16;
    int r = idx & 65535;
    int k = r >> 6;
    int c = r & 63;
    const float* W = (y == 0) ? Wq : (y == 1) ? Wk : Wv;
    float x = W[r];
    unsigned short h = f2bf(x);
    unsigned short l = f2bf(x - bf2f(h));
    int o = (y * 64 + c) * 1024 + k;
    wt_hi[o] = h; wt_lo[o] = l;
}

// ---------------------------------------------------------------------------
// Kernel 2: projection. grid (3, 256): x = which matrix (q/k/v), y = m-tile
// of 64 rows. M-tile 64 (was 128): LDS 36.9 KB -> 4 blocks/CU, grid 768
// -> 3 blocks/CU resident (was 1.5). Compensated bf16 MFMA (hh+hl+lh ~ fp32).
// y==0 -> q_hi/q_lo bf16; y==1 -> k bf16; y==2 -> V^T [b][d][s] bf16.
// ---------------------------------------------------------------------------
__global__ __launch_bounds__(256, 4) void proj_kernel(
    const float* __restrict__ X,
    const unsigned short* __restrict__ wt_hi, const unsigned short* __restrict__ wt_lo,
    const float* __restrict__ bq, const float* __restrict__ bk, const float* __restrict__ bv,
    unsigned short* __restrict__ q_hi, unsigned short* __restrict__ q_lo,
    unsigned short* __restrict__ k_bf, unsigned short* __restrict__ vt_g)
{
    __shared__ __align__(16) unsigned short a_hi[64][72];   // X tile hi, +8 pad
    __shared__ __align__(16) unsigned short a_lo[64][72];
    __shared__ __align__(16) unsigned short b_hi[64][72];   // W^T tile hi [col][k]
    __shared__ __align__(16) unsigned short b_lo[64][72];

    const int tid  = threadIdx.x;
    const int lane = tid & 63;
    const int w    = tid >> 6;
    const int quad = lane >> 4;
    const int l15  = lane & 15;
    const int y    = blockIdx.x;        // 0=q 1=k 2=v
    const int m0   = blockIdx.y * 64;   // global row (b*4096+s)

    fx4 acc[4];
    #pragma unroll
    for (int nt = 0; nt < 4; nt++)
        acc[nt] = (fx4){0.f, 0.f, 0.f, 0.f};

    for (int kc = 0; kc < 16; kc++) {
        // stage X tile 64x64 fp32 -> hi/lo bf16 in LDS (coalesced 16B reads)
        #pragma unroll
        for (int i = 0; i < 4; i++) {
            int c = tid + i * 256;
            int row = c >> 4;
            int off = (c & 15) * 4;
            const float* src = X + (size_t)(m0 + row) * 1024 + kc * 64 + off;
            fx4 xv = *(const fx4*)src;
            unsigned short h0 = f2bf(xv.x), h1 = f2bf(xv.y), h2 = f2bf(xv.z), h3 = f2bf(xv.w);
            unsigned short l0 = f2bf(xv.x - bf2f(h0)), l1 = f2bf(xv.y - bf2f(h1));
            unsigned short l2 = f2bf(xv.z - bf2f(h2)), l3 = f2bf(xv.w - bf2f(h3));
            *(u16x4*)&a_hi[row][off] = (u16x4){h0, h1, h2, h3};
            *(u16x4*)&a_lo[row][off] = (u16x4){l0, l1, l2, l3};
        }
        // stage W^T tile 64x64 (pre-split, coalesced 16B reads)
        #pragma unroll
        for (int i = 0; i < 2; i++) {
            int c = tid + i * 256;
            int row = c >> 3;
            int off = (c & 7) * 8;
            size_t g = (size_t)(y * 64 + row) * 1024 + kc * 64 + off;
            *(s16x8*)&b_hi[row][off] = *(const s16x8*)(wt_hi + g);
            *(s16x8*)&b_lo[row][off] = *(const s16x8*)(wt_lo + g);
        }
        __syncthreads();

        s16x8 ah[2], al[2];
        #pragma unroll
        for (int ks = 0; ks < 2; ks++) {
            int r = w * 16 + l15;
            ah[ks] = *(const s16x8*)&a_hi[r][ks * 32 + quad * 8];
            al[ks] = *(const s16x8*)&a_lo[r][ks * 32 + quad * 8];
        }
        #pragma unroll
        for (int nt = 0; nt < 4; nt++) {
            #pragma unroll
            for (int ks = 0; ks < 2; ks++) {
                s16x8 bh = *(const s16x8*)&b_hi[nt * 16 + l15][ks * 32 + quad * 8];
                s16x8 bl = *(const s16x8*)&b_lo[nt * 16 + l15][ks * 32 + quad * 8];
                acc[nt] = __builtin_amdgcn_mfma_f32_16x16x32_bf16(ah[ks], bh, acc[nt], 0, 0, 0);
                acc[nt] = __builtin_amdgcn_mfma_f32_16x16x32_bf16(ah[ks], bl, acc[nt], 0, 0, 0);
                acc[nt] = __builtin_amdgcn_mfma_f32_16x16x32_bf16(al[ks], bh, acc[nt], 0, 0, 0);
            }
        }
        __syncthreads();
    }

    // epilogue: bias + relu, write per-matrix
    const float* bias = (y == 0) ? bq : (y == 1) ? bk : bv;
    const int b   = m0 >> 12;
    const int s0b = m0 & 4095;
    unsigned short* vtr = (unsigned short*)&a_hi[0][0];  // alias: [64 d][72] (s-padded)

    #pragma unroll
    for (int nt = 0; nt < 4; nt++) {
        int col = nt * 16 + l15;
        float bb = bias[col];
        int rloc = w * 16 + quad * 4;   // local row 0..63
        #pragma unroll
        for (int r = 0; r < 4; r++) {
            float v = acc[nt][r] + bb;
            v = fmaxf(v, 0.f);
            size_t grow = (size_t)(m0 + rloc + r);
            if (y == 0) {
                unsigned short h = f2bf(v);
                unsigned short l = f2bf(v - bf2f(h));
                q_hi[grow * 64 + col] = h;
                q_lo[grow * 64 + col] = l;
            } else if (y == 1) {
                k_bf[grow * 64 + col] = f2bf(v);
            } else {
                vtr[col * 72 + rloc + r] = f2bf(v);  // transpose via LDS
            }
        }
    }
    if (y == 2) {
        __syncthreads();
        #pragma unroll
        for (int i = 0; i < 2; i++) {
            int c = tid + i * 256;
            int row = c >> 3;           // d 0..63
            int off = (c & 7) * 8;      // s chunk
            s16x8 vv = *(const s16x8*)&vtr[row * 72 + off];
            *(s16x8*)(vt_g + (size_t)(b * 64 + row) * 4096 + s0b + off) = vv;
        }
    }
}

// ---------------------------------------------------------------------------
// Kernel 3: fused attention, KV-split. grid 1024 = (b,4)(chunk,4)(qtile,64).
// Each block: 64 q-rows x 1024 keys (16 KV tiles). Writes UNNORMALIZED
// partial O and partial row-sum l; combine kernel reduces over chunks.
// No online max: q,k >= 0 post-relu => scores in [0, ~20], exp safe in fp32,
// partials combine by pure addition.
// ---------------------------------------------------------------------------
__global__ __launch_bounds__(256) void attn_kernel(
    const unsigned short* __restrict__ q_hi, const unsigned short* __restrict__ q_lo,
    const unsigned short* __restrict__ k_bf, const unsigned short* __restrict__ vt_g,
    float* __restrict__ pO, float* __restrict__ pL)
{
    __shared__ __align__(16) unsigned short kt[64][72];      // [key][dim]
    __shared__ __align__(16) unsigned short vt[64][72];      // [dim][key]  (V^T)
    __shared__ __align__(16) unsigned short pt[4][16][72];   // per-wave P [q][key]

    const int tid  = threadIdx.x;
    const int lane = tid & 63;
    const int w    = tid >> 6;
    const int quad = lane >> 4;
    const int l15  = lane & 15;
    const int idx  = blockIdx.x;
    const int qt   = idx & 63;
    const int ck   = (idx >> 6) & 3;     // key chunk (1024 keys)
    const int b    = idx >> 8;
    const int q0   = qt * 64;            // within batch

    // Q fragments (A layout: m=lane&15, k=quad*8+j), split hi/lo
    const size_t qoff = ((size_t)b * 4096 + q0 + w * 16 + l15) * 64 + quad * 8;
    s16x8 qh0 = *(const s16x8*)(q_hi + qoff);
    s16x8 qh1 = *(const s16x8*)(q_hi + qoff + 32);
    s16x8 ql0 = *(const s16x8*)(q_lo + qoff);
    s16x8 ql1 = *(const s16x8*)(q_lo + qoff + 32);

    fx4 accO[4];
    #pragma unroll
    for (int nt = 0; nt < 4; nt++) accO[nt] = (fx4){0.f, 0.f, 0.f, 0.f};
    float lpart[4] = {0.f, 0.f, 0.f, 0.f};

    const unsigned short* kgb = k_bf + (size_t)b * 4096 * 64;  // [s][64]
    const unsigned short* vgb = vt_g + (size_t)b * 64 * 4096;  // [d][s]

    for (int it = ck * 16; it < ck * 16 + 16; it++) {
        const unsigned short* kg = kgb + (size_t)it * 4096;    // 64 keys x 64 dims, contiguous
        #pragma unroll
        for (int i = 0; i < 2; i++) {
            int c = tid + i * 256;
            int row = c >> 3;
            int off = (c & 7) * 8;
            *(s16x8*)&kt[row][off] = *(const s16x8*)(kg + c * 8);
            *(s16x8*)&vt[row][off] = *(const s16x8*)(vgb + (size_t)row * 4096 + it * 64 + off);
        }
        __syncthreads();

        // S = Q K^T  (q hi/lo compensated)
        fx4 sc[4];
        #pragma unroll
        for (int nt = 0; nt < 4; nt++) sc[nt] = (fx4){0.f, 0.f, 0.f, 0.f};
        #pragma unroll
        for (int nt = 0; nt < 4; nt++) {
            s16x8 k0 = *(const s16x8*)&kt[nt * 16 + l15][quad * 8];
            s16x8 k1 = *(const s16x8*)&kt[nt * 16 + l15][32 + quad * 8];
            sc[nt] = __builtin_amdgcn_mfma_f32_16x16x32_bf16(qh0, k0, sc[nt], 0, 0, 0);
            sc[nt] = __builtin_amdgcn_mfma_f32_16x16x32_bf16(ql0, k0, sc[nt], 0, 0, 0);
            sc[nt] = __builtin_amdgcn_mfma_f32_16x16x32_bf16(qh1, k1, sc[nt], 0, 0, 0);
            sc[nt] = __builtin_amdgcn_mfma_f32_16x16x32_bf16(ql1, k1, sc[nt], 0, 0, 0);
        }

        // P = exp(S); accumulate row-sums per-lane; P -> LDS (C layout -> A layout)
        #pragma unroll
        for (int nt = 0; nt < 4; nt++) {
            #pragma unroll
            for (int r = 0; r < 4; r++) {
                float p = __builtin_amdgcn_exp2f(sc[nt][r] * LOG2E);
                unsigned short pb = f2bf(p);
                lpart[r] += bf2f(pb);   // denominator matches bf16-rounded numerator
                pt[w][quad * 4 + r][nt * 16 + l15] = pb;
            }
        }

        // O += P V
        s16x8 pa0 = *(const s16x8*)&pt[w][l15][quad * 8];
        s16x8 pa1 = *(const s16x8*)&pt[w][l15][32 + quad * 8];
        #pragma unroll
        for (int nt = 0; nt < 4; nt++) {
            s16x8 v0 = *(const s16x8*)&vt[nt * 16 + l15][quad * 8];
            s16x8 v1 = *(const s16x8*)&vt[nt * 16 + l15][32 + quad * 8];
            accO[nt] = __builtin_amdgcn_mfma_f32_16x16x32_bf16(pa0, v0, accO[nt], 0, 0, 0);
            accO[nt] = __builtin_amdgcn_mfma_f32_16x16x32_bf16(pa1, v1, accO[nt], 0, 0, 0);
        }
        __syncthreads();
    }

    // reduce row-sums across the 16 lanes sharing each row group
    #pragma unroll
    for (int r = 0; r < 4; r++) {
        float v = lpart[r];
        #pragma unroll
        for (int o = 1; o < 16; o <<= 1) v += __shfl_xor(v, o);
        lpart[r] = v;
    }
    // write partials: pO[ck][b*4096+q][64], pL[ck][b*4096+q]
    #pragma unroll
    for (int r = 0; r < 4; r++) {
        int qrow = q0 + w * 16 + quad * 4 + r;
        size_t grow = (size_t)b * 4096 + qrow;
        #pragma unroll
        for (int nt = 0; nt < 4; nt++)
            pO[((size_t)ck * 16384 + grow) * 64 + nt * 16 + l15] = accO[nt][r];
        if (l15 == 0)
            pL[(size_t)ck * 16384 + grow] = lpart[r];
    }
}

// ---------------------------------------------------------------------------
// Kernel 4: combine partials: out = (sum_c pO) * mask / (sum_c pL)
// ---------------------------------------------------------------------------
__global__ __launch_bounds__(256) void combine_kernel(
    const float* __restrict__ pO, const float* __restrict__ pL,
    const float* __restrict__ mask, float* __restrict__ out)
{
    int idx = blockIdx.x * 256 + threadIdx.x;   // 262144 = (b*4096+s)*16 + dgrp
    int q  = idx >> 4;
    int dg = idx & 15;
    fx4 s = (fx4){0.f, 0.f, 0.f, 0.f};
    float l = 0.f;
    #pragma unroll
    for (int c = 0; c < 4; c++) {
        s += *(const fx4*)(pO + ((size_t)c * 16384 + q) * 64 + dg * 4);
        l += pL[(size_t)c * 16384 + q];
    }
    float scale = mask[q] / l;
    *(fx4*)(out + (size_t)q * 64 + dg * 4) = s * scale;
}

// ---------------------------------------------------------------------------
extern "C" void kernel_launch(void* const* d_in, const int* in_sizes, int n_in,
                              void* d_out, int out_size, void* d_ws, size_t ws_size,
                              hipStream_t stream)
{
    const float* X    = (const float*)d_in[0];
    const float* mask = (const float*)d_in[1];
    const float* Wq   = (const float*)d_in[2];
    const float* bq   = (const float*)d_in[3];
    const float* Wk   = (const float*)d_in[4];
    const float* bk   = (const float*)d_in[5];
    const float* Wv   = (const float*)d_in[6];
    const float* bv   = (const float*)d_in[7];
    float* out = (float*)d_out;

    char* ws = (char*)d_ws;
    unsigned short* q_hi  = (unsigned short*)(ws);                       // 2 MB
    unsigned short* q_lo  = (unsigned short*)(ws + (size_t)(2u << 20));  // 2 MB
    unsigned short* k_bf  = (unsigned short*)(ws + (size_t)(4u << 20));  // 2 MB
    unsigned short* vt_g  = (unsigned short*)(ws + (size_t)(6u << 20));  // 2 MB  [b][d][s]
    unsigned short* wt_hi = (unsigned short*)(ws + (size_t)(8u << 20));  // 384 KB
    unsigned short* wt_lo = (unsigned short*)(ws + (size_t)(8u << 20) + 393216);
    float*          pO    = (float*)(ws + (size_t)(9u << 20));           // 16 MB [4][16384][64]
    float*          pL    = (float*)(ws + (size_t)(25u << 20));          // 256 KB [4][16384]

    hipLaunchKernelGGL(prep_w_kernel, dim3(768), dim3(256), 0, stream,
                       Wq, Wk, Wv, wt_hi, wt_lo);
    hipLaunchKernelGGL(proj_kernel, dim3(3, 256), dim3(256), 0, stream,
                       X, wt_hi, wt_lo, bq, bk, bv, q_hi, q_lo, k_bf, vt_g);
    hipLaunchKernelGGL(attn_kernel, dim3(1024), dim3(256), 0, stream,
                       q_hi, q_lo, k_bf, vt_g, pO, pL);
    hipLaunchKernelGGL(combine_kernel, dim3(1024), dim3(256), 0, stream,
                       pO, pL, mask, out);
}